// Round 3
// baseline (1825.927 us; speedup 1.0000x reference)
//
#include <hip/hip_runtime.h>
#include <hip/hip_bf16.h>
#include <cmath>
#include <cstdint>

using bf16 = __bf16;
typedef __bf16 bf16x8 __attribute__((ext_vector_type(8)));
typedef float f32x4 __attribute__((ext_vector_type(4)));

#define DEVI __device__ __forceinline__

// physical 16B-chunk index for logical (row m, chunk c) in a [128][32]-bf16 LDS
// tile, XOR-swizzled: 16-lane column reads spread over all 32 banks ~2-way
// (free, m136) instead of 16-way. XOR is an involution -> same map both sides.
DEVI int pcidx(int m, int c) { return (m << 2) + (c ^ ((m >> 1) & 3)); }

DEVI void gload16(const void* g, void* l) {
  __builtin_amdgcn_global_load_lds(
      (const __attribute__((address_space(1))) void*)g,
      (__attribute__((address_space(3))) void*)l, 16, 0, 0);
}

// ---------------------------------------------------------------------------
// GEMM: C[M x Ncols] = act( A[M x K] @ B[K x N] * scale )
// B stored transposed+padded: Bt[Npad][K] bf16, K multiple of 32.
// A: bf16 [Mpad][K] (AF32=false) staged via global_load_lds (dest wave-uniform
// base + lane*16, source pre-swizzled; rule #21), or fp32 [Mreal][ldA]
// (AF32=true) staged via registers with on-the-fly bf16 convert + K-tail pad.
// Grid: 1D, NB*NT blocks; n-tile fastest + bijective XCD chunk swizzle (m204)
// so both column tiles of a row-block share an XCD -> A-slab L2 reuse.
// ACT: 0 = f32 store (x*scale), 1 = bf16 relu, 2 = bf16 sigmoid,
//      3 = bf16 tanh, 4 = f32 tanh
// ---------------------------------------------------------------------------
template <int ACT, bool AF32>
__global__ __launch_bounds__(256) void gemm_k(
    const void* __restrict__ Ap, const bf16* __restrict__ Bt,
    void* __restrict__ Cp, int Mreal, int K, int ldA, int Ncols, int ldC,
    float scale, int NT) {
  __shared__ __align__(16) bf16 lA[128 * 32];
  __shared__ __align__(16) bf16 lB[128 * 32];
  const int tid = threadIdx.x;
  // ---- bijective XCD chunk swizzle (works for any nwg; ERRATA #11) ----
  const int nwg = gridDim.x;
  const int q8 = nwg >> 3, r8 = nwg & 7;
  const int xcd = blockIdx.x & 7, idx = blockIdx.x >> 3;
  const int wgid =
      (xcd < r8 ? xcd * (q8 + 1) : r8 * (q8 + 1) + (xcd - r8) * q8) + idx;
  const int m0 = (wgid / NT) * 128, n0 = (wgid % NT) * 128;

  const int w = tid >> 6, lane = tid & 63;
  const int wm = w >> 1, wn = w & 1;
  const int lm = lane & 15, lg = lane >> 4;

  f32x4 acc[4][4] = {};

  const int nkt = K / 32;
  for (int kt = 0; kt < nkt; ++kt) {
    const int k0 = kt * 32;
    // ---- B staging: 2 x global_load_lds, global source pre-swizzled ----
#pragma unroll
    for (int i = 0; i < 2; i++) {
      int q = i * 256 + tid;
      int row = q >> 2, slot = q & 3;
      int c = slot ^ ((row >> 1) & 3);
      const bf16* src = Bt + (size_t)(n0 + row) * K + k0 + c * 8;
      bf16* dst = lB + (size_t)(i * 256 + (tid & 192)) * 8;  // wave-uniform
      gload16(src, dst);
    }
    // ---- A staging ----
    if constexpr (AF32) {
      const float* Af = (const float*)Ap;
      int row = tid >> 1, h = tid & 1;
      int gm = m0 + row;
      int kb = k0 + h * 16;
      const float* Ar = Af + (size_t)gm * ldA;
      bf16x8 v0, v1;
      if (gm < Mreal && kb + 16 <= ldA) {
        f32x4 f0 = *(const f32x4*)(Ar + kb);
        f32x4 f1 = *(const f32x4*)(Ar + kb + 4);
        f32x4 f2 = *(const f32x4*)(Ar + kb + 8);
        f32x4 f3 = *(const f32x4*)(Ar + kb + 12);
#pragma unroll
        for (int j = 0; j < 4; j++) {
          v0[j] = (bf16)f0[j];
          v0[4 + j] = (bf16)f1[j];
          v1[j] = (bf16)f2[j];
          v1[4 + j] = (bf16)f3[j];
        }
      } else {
#pragma unroll
        for (int j = 0; j < 8; j++) {
          v0[j] = (bf16)((gm < Mreal && kb + j < ldA) ? Ar[kb + j] : 0.f);
          v1[j] = (bf16)((gm < Mreal && kb + 8 + j < ldA) ? Ar[kb + 8 + j] : 0.f);
        }
      }
      *(bf16x8*)&lA[(size_t)pcidx(row, h * 2) * 8] = v0;
      *(bf16x8*)&lA[(size_t)pcidx(row, h * 2 + 1) * 8] = v1;
    } else {
      const bf16* Ab = (const bf16*)Ap;
#pragma unroll
      for (int i = 0; i < 2; i++) {
        int q = i * 256 + tid;
        int row = q >> 2, slot = q & 3;
        int c = slot ^ ((row >> 1) & 3);
        const bf16* src = Ab + (size_t)(m0 + row) * K + k0 + c * 8;
        bf16* dst = lA + (size_t)(i * 256 + (tid & 192)) * 8;
        gload16(src, dst);
      }
    }
    asm volatile("s_waitcnt vmcnt(0)" ::: "memory");
    __syncthreads();
    // ---- compute: 8 ds_read_b128 + 16 MFMA per wave ----
    bf16x8 af[4], bfr[4];
#pragma unroll
    for (int mi = 0; mi < 4; ++mi) {
      int m = wm * 64 + mi * 16 + lm;
      af[mi] = *(const bf16x8*)&lA[(size_t)pcidx(m, lg) * 8];
    }
#pragma unroll
    for (int ni = 0; ni < 4; ++ni) {
      int n = wn * 64 + ni * 16 + lm;
      bfr[ni] = *(const bf16x8*)&lB[(size_t)pcidx(n, lg) * 8];
    }
#pragma unroll
    for (int mi = 0; mi < 4; ++mi)
#pragma unroll
      for (int ni = 0; ni < 4; ++ni)
        acc[mi][ni] = __builtin_amdgcn_mfma_f32_16x16x32_bf16(
            af[mi], bfr[ni], acc[mi][ni], 0, 0, 0);
    __syncthreads();
  }
  // ---- epilogue: D col = lane&15, row = (lane>>4)*4 + reg (m89-verified) ----
#pragma unroll
  for (int mi = 0; mi < 4; ++mi) {
#pragma unroll
    for (int ni = 0; ni < 4; ++ni) {
#pragma unroll
      for (int r = 0; r < 4; ++r) {
        int row = m0 + wm * 64 + mi * 16 + lg * 4 + r;
        int col = n0 + wn * 64 + ni * 16 + lm;
        if (row < Mreal && col < Ncols) {
          float x = acc[mi][ni][r] * scale;
          if constexpr (ACT == 0)
            ((float*)Cp)[(size_t)row * ldC + col] = x;
          else if constexpr (ACT == 1)
            ((bf16*)Cp)[(size_t)row * ldC + col] = (bf16)fmaxf(x, 0.f);
          else if constexpr (ACT == 2)
            ((bf16*)Cp)[(size_t)row * ldC + col] = (bf16)(1.f / (1.f + __expf(-x)));
          else if constexpr (ACT == 3)
            ((bf16*)Cp)[(size_t)row * ldC + col] = (bf16)tanhf(x);
          else
            ((float*)Cp)[(size_t)row * ldC + col] = tanhf(x);
        }
      }
    }
  }
}

// ---------------------------------------------------------------------------
// Weight transpose+pad+convert: dst[Np][Kp] bf16,
// dst[n*Kp + cofs + k] = (k<K && n<Nsrc) ? src[k*sN + n] : 0
// One launch covers all 11 weight tensors.
// ---------------------------------------------------------------------------
struct WJob {
  const float* src;
  bf16* dst;
  int Np, W, K, Nsrc, sN, Kp, cofs, kch, blkEnd;
};
struct WJobs { WJob j[11]; };

__global__ void wcvt_k(WJobs J) {
  int b = blockIdx.x;
  int ji = 0;
  while (b >= J.j[ji].blkEnd) ji++;
  const WJob job = J.j[ji];
  int lb = b - (ji ? J.j[ji - 1].blkEnd : 0);
  int n = lb / job.kch, bk = lb % job.kch;
  int k = bk * 256 + (int)threadIdx.x;
  if (k >= job.W) return;
  float v = 0.f;
  if (k < job.K && n < job.Nsrc) v = job.src[(size_t)k * job.sN + n];
  job.dst[(size_t)n * job.Kp + job.cofs + k] = (bf16)v;
}

// w2rs[v*256+k] = sum_d w2_v[k][d]  (for the pool_view GEMV)
__global__ void w2rs_k(const float* w0, const float* w1, const float* w2,
                       float* out) {
  int v = blockIdx.x, k = threadIdx.x;
  const float* w = v == 0 ? w0 : (v == 1 ? w1 : w2);
  float s = 0.f;
  for (int d = 0; d < 256; d++) s += w[(size_t)k * 256 + d];
  out[v * 256 + k] = s;
}

// ---------------------------------------------------------------------------
// Gating: per node -> pool_view, view_x, feat_x; writes c[N,288] bf16
// (c = [view_x(3) | feat_x(256) | zero-pad(29)]) and pool_view[N,4] f32.
// pool_view[n,v] = (t_v[n,:] . rowsum(w2_v)) / 256  -- h never materialized.
// ---------------------------------------------------------------------------
__global__ __launch_bounds__(256) void gate_k(
    const bf16* __restrict__ t, const float* __restrict__ pf,
    const float* __restrict__ w2rs, const float* __restrict__ vw1,
    const float* __restrict__ vw2, const float* __restrict__ fw1,
    const float* __restrict__ fw2, bf16* __restrict__ c,
    float* __restrict__ pv) {
  int n = blockIdx.x, i = threadIdx.x;
  __shared__ float pfs[256];
  __shared__ float red[12];
  __shared__ float us[16];
  __shared__ float pvv[3], vx[3];
  size_t tb = (size_t)n * 768;
  float s0 = (float)t[tb + i] * w2rs[i];
  float s1 = (float)t[tb + 256 + i] * w2rs[256 + i];
  float s2 = (float)t[tb + 512 + i] * w2rs[512 + i];
#pragma unroll
  for (int o = 32; o > 0; o >>= 1) {
    s0 += __shfl_xor(s0, o);
    s1 += __shfl_xor(s1, o);
    s2 += __shfl_xor(s2, o);
  }
  int wv = i >> 6;
  if ((i & 63) == 0) { red[wv] = s0; red[4 + wv] = s1; red[8 + wv] = s2; }
  pfs[i] = pf[(size_t)n * 256 + i];
  __syncthreads();
  if (i == 0) {
    float p0 = (red[0] + red[1] + red[2] + red[3]) * (1.f / 256.f);
    float p1 = (red[4] + red[5] + red[6] + red[7]) * (1.f / 256.f);
    float p2 = (red[8] + red[9] + red[10] + red[11]) * (1.f / 256.f);
    pvv[0] = p0; pvv[1] = p1; pvv[2] = p2;
    float s = p0 * vw1[0] + p1 * vw1[1] + p2 * vw1[2];
    float a = fmaxf(s, 0.f);
    vx[0] = 1.f / (1.f + __expf(-a * vw2[0]));
    vx[1] = 1.f / (1.f + __expf(-a * vw2[1]));
    vx[2] = 1.f / (1.f + __expf(-a * vw2[2]));
  }
  // feat_x: us[16] = relu(pf @ fw1[256,16]); 16 groups of 16 lanes
  int j = i >> 4, l16 = i & 15;
  __syncthreads();
  float p = 0.f;
#pragma unroll
  for (int kk = 0; kk < 16; kk++) {
    int k = l16 * 16 + kk;
    p += pfs[k] * fw1[k * 16 + j];
  }
#pragma unroll
  for (int o = 8; o > 0; o >>= 1) p += __shfl_xor(p, o, 16);
  if (l16 == 0) us[j] = fmaxf(p, 0.f);
  __syncthreads();
  float fx = 0.f;
#pragma unroll
  for (int jj = 0; jj < 16; jj++) fx += us[jj] * fw2[jj * 256 + i];
  float fxs = 1.f / (1.f + __expf(-fx));
  size_t cb = (size_t)n * 288;
  c[cb + 3 + i] = (bf16)fxs;
  if (i < 3) { c[cb + i] = (bf16)vx[i]; pv[(size_t)n * 4 + i] = pvv[i]; }
  if (i < 29) c[cb + 259 + i] = (bf16)0.f;
}

// z = concat(view_w*pool_view, feat_w*pool_feat), K-padded to 288, bf16
__global__ void kz_k(const bf16* __restrict__ wall, const float* __restrict__ pf,
                     const float* __restrict__ pv, bf16* __restrict__ z) {
  int n = blockIdx.x, t = threadIdx.x;
  size_t zb = (size_t)n * 288;
  float f = (float)wall[zb + 3 + t] * pf[(size_t)n * 256 + t];
  z[zb + 3 + t] = (bf16)f;
  if (t < 3) z[zb + t] = (bf16)((float)wall[zb + t] * pv[(size_t)n * 4 + t]);
  if (t < 29) z[zb + 259 + t] = (bf16)0.f;
}

// ---------------- CSR build (counting sort by row) ----------------
__global__ void zero_k(int* p, int n) {
  int i = blockIdx.x * 256 + threadIdx.x;
  if (i < n) p[i] = 0;
}
__global__ void hist_k(const int* __restrict__ row, int* __restrict__ cnt, int E) {
  int e = blockIdx.x * 256 + threadIdx.x;
  if (e < E) atomicAdd(&cnt[row[e]], 1);
}
__global__ void s1_k(const int* cnt, int* bsum, int n) {
  __shared__ int sh[256];
  int i = blockIdx.x * 256 + threadIdx.x;
  sh[threadIdx.x] = (i < n) ? cnt[i] : 0;
  __syncthreads();
  for (int o = 128; o > 0; o >>= 1) {
    if ((int)threadIdx.x < o) sh[threadIdx.x] += sh[threadIdx.x + o];
    __syncthreads();
  }
  if (threadIdx.x == 0) bsum[blockIdx.x] = sh[0];
}
__global__ void s2_k(const int* bsum, int* bofs, int nb) {
  __shared__ int sh[256];
  int t = threadIdx.x;
  int v = (t < nb) ? bsum[t] : 0;
  sh[t] = v;
  __syncthreads();
  for (int o = 1; o < 256; o <<= 1) {
    int add = (t >= o) ? sh[t - o] : 0;
    __syncthreads();
    sh[t] += add;
    __syncthreads();
  }
  if (t < nb) bofs[t] = sh[t] - v;
}
__global__ void s3_k(const int* cnt, const int* bofs, int* starts, int* cursor,
                     int n, int total) {
  __shared__ int sh[256];
  int t = threadIdx.x, i = blockIdx.x * 256 + t;
  int v = (i < n) ? cnt[i] : 0;
  sh[t] = v;
  __syncthreads();
  for (int o = 1; o < 256; o <<= 1) {
    int add = (t >= o) ? sh[t - o] : 0;
    __syncthreads();
    sh[t] += add;
    __syncthreads();
  }
  if (i < n) {
    int ex = bofs[blockIdx.x] + sh[t] - v;
    starts[i] = ex;
    cursor[i] = ex;
  }
  if (i == 0) starts[n] = total;
}
__global__ void scat_k(const int* __restrict__ row, const int* __restrict__ col,
                       const float* __restrict__ val, int* __restrict__ cursor,
                       int* __restrict__ ccol, float* __restrict__ cval, int E) {
  int e = blockIdx.x * 256 + threadIdx.x;
  if (e < E) {
    int r = row[e];
    int p = atomicAdd(&cursor[r], 1);
    ccol[p] = col[e];
    cval[p] = val[e];
  }
}

// spmm: s[r,:] = sum_e val_e * z[col_e,:], one block per row, 288 cols
__global__ __launch_bounds__(256) void spmm_k(
    const int* __restrict__ starts, const int* __restrict__ ccol,
    const float* __restrict__ cval, const bf16* __restrict__ z,
    bf16* __restrict__ s) {
  int r = blockIdx.x, t = threadIdx.x;
  int e0 = starts[r], e1 = starts[r + 1];
  float a0 = 0.f, a1 = 0.f;
  for (int e = e0; e < e1; e++) {
    int c = ccol[e];
    float v = cval[e];
    size_t zb = (size_t)c * 288;
    a0 += v * (float)z[zb + t];
    if (t < 32) a1 += v * (float)z[zb + 256 + t];
  }
  size_t sb = (size_t)r * 288;
  s[sb + t] = (bf16)a0;
  if (t < 32) s[sb + 256 + t] = (bf16)a1;
}

// ---------------------------------------------------------------------------
extern "C" void kernel_launch(void* const* d_in, const int* in_sizes, int n_in,
                              void* d_out, int out_size, void* d_ws,
                              size_t ws_size, hipStream_t stream) {
  const float* x0 = (const float*)d_in[0];
  const float* p0w1 = (const float*)d_in[1];
  const float* p0w2 = (const float*)d_in[2];
  const float* x1 = (const float*)d_in[3];
  const float* p1w1 = (const float*)d_in[4];
  const float* p1w2 = (const float*)d_in[5];
  const float* x2 = (const float*)d_in[6];
  const float* p2w1 = (const float*)d_in[7];
  const float* p2w2 = (const float*)d_in[8];
  const int* erow = (const int*)d_in[9];
  const int* ecol = (const int*)d_in[10];
  const float* evalp = (const float*)d_in[11];
  const float* vw1 = (const float*)d_in[12];
  const float* vw2 = (const float*)d_in[13];
  const float* fw1 = (const float*)d_in[14];
  const float* fw2 = (const float*)d_in[15];
  const float* m1 = (const float*)d_in[16];
  const float* m2 = (const float*)d_in[17];
  const float* g0 = (const float*)d_in[18];
  const float* g1 = (const float*)d_in[19];
  const float* g2 = (const float*)d_in[20];

  const int N = 50000;
  const int MP = 50048;  // 391 * 128
  const int NB = 391;
  const int E = in_sizes[9];

  char* p = (char*)d_ws;
  auto alloc = [&](size_t bytes) -> char* {
    char* r = p;
    p += (bytes + 255) & ~(size_t)255;
    return r;
  };
  bf16* t = (bf16*)alloc((size_t)MP * 768 * 2);  // 76.9 MB; dead after gate_k
  bf16* w1T0 = (bf16*)alloc((size_t)256 * 1024 * 2);
  bf16* w1T1 = (bf16*)alloc((size_t)256 * 832 * 2);
  bf16* w1T2 = (bf16*)alloc((size_t)256 * 640 * 2);
  bf16* W2sT = (bf16*)alloc((size_t)256 * 768 * 2);
  float* w2rs = (float*)alloc(768 * 4);
  bf16* m1T = (bf16*)alloc((size_t)128 * 288 * 2);
  bf16* m2T = (bf16*)alloc((size_t)384 * 128 * 2);
  bf16* g0T = (bf16*)alloc((size_t)384 * 288 * 2);
  bf16* g1T = (bf16*)alloc((size_t)384 * 288 * 2);
  bf16* g2T = (bf16*)alloc((size_t)128 * 288 * 2);
  float* pf = (float*)alloc((size_t)N * 256 * 4);
  float* pv = (float*)alloc((size_t)N * 4 * 4);
  bf16* c = (bf16*)alloc((size_t)MP * 288 * 2);
  int* cnt = (int*)alloc((size_t)50004 * 4);
  int* starts = (int*)alloc((size_t)50004 * 4);
  int* cursor = (int*)alloc((size_t)50004 * 4);
  int* bsum = (int*)alloc(1024);
  int* bofs = (int*)alloc(1024);
  int* ccol = (int*)alloc((size_t)E * 4);
  float* cval = (float*)alloc((size_t)E * 4);
  // aliases into t's region (t dead after gate_k; stream order serializes):
  //   u    = t[ 0      .. MP*128 )   (m1-gemm out, dead after m2-gemm)
  //   wall = t[ MP*128 .. MP*416 )   (m2-gemm out, dead after kz)
  //   z    = t[ MP*416 .. MP*704 )   (live through GCN; 704 <= 768)
  bf16* u = t;
  bf16* wall = t + (size_t)MP * 128;
  bf16* z = t + (size_t)MP * 416;
  bf16* s = c;  // c dead after the m1 GEMM; spmm output reuses it
  if ((size_t)(p - (char*)d_ws) > ws_size) return;  // ws too small: bail

  // ---- weight convert/transpose jobs ----
  WJobs J;
  auto setj = [&](int idx, const float* src, bf16* dst, int Np, int W, int K,
                  int Nsrc, int sN, int Kp, int cofs) {
    WJob& jj = J.j[idx];
    jj.src = src; jj.dst = dst; jj.Np = Np; jj.W = W; jj.K = K; jj.Nsrc = Nsrc;
    jj.sN = sN; jj.Kp = Kp; jj.cofs = cofs; jj.kch = (W + 255) / 256;
    jj.blkEnd = 0;
  };
  setj(0, p0w1, w1T0, 256, 1024, 1000, 256, 256, 1024, 0);
  setj(1, p1w1, w1T1, 256, 832, 800, 256, 256, 832, 0);
  setj(2, p2w1, w1T2, 256, 640, 600, 256, 256, 640, 0);
  setj(3, p0w2, W2sT, 256, 256, 256, 256, 256, 768, 0);
  setj(4, p1w2, W2sT, 256, 256, 256, 256, 256, 768, 256);
  setj(5, p2w2, W2sT, 256, 256, 256, 256, 256, 768, 512);
  setj(6, m1, m1T, 128, 288, 259, 128, 128, 288, 0);
  setj(7, m2, m2T, 384, 128, 128, 259, 259, 128, 0);
  setj(8, g0, g0T, 384, 288, 259, 259, 259, 288, 0);
  setj(9, g1, g1T, 384, 288, 259, 259, 259, 288, 0);
  setj(10, g2, g2T, 128, 288, 259, 10, 10, 288, 0);
  int cum = 0;
  for (int i = 0; i < 11; i++) {
    cum += J.j[i].Np * J.j[i].kch;
    J.j[i].blkEnd = cum;
  }
  wcvt_k<<<cum, 256, 0, stream>>>(J);
  w2rs_k<<<3, 256, 0, stream>>>(p0w2, p1w2, p2w2, w2rs);

  // ---- per-view projections: t_v = relu(x_v @ w1_v), bf16 [N,768] ----
  gemm_k<1, true><<<NB * 2, 256, 0, stream>>>(x0, w1T0, t, N, 1024, 1000, 256, 768, 1.f, 2);
  gemm_k<1, true><<<NB * 2, 256, 0, stream>>>(x1, w1T1, t + 256, N, 832, 800, 256, 768, 1.f, 2);
  gemm_k<1, true><<<NB * 2, 256, 0, stream>>>(x2, w1T2, t + 512, N, 640, 600, 256, 768, 1.f, 2);
  // ---- pool_feat = (t @ [w2_0;w2_1;w2_2]) / 3, f32 [N,256] ----
  gemm_k<0, false><<<NB * 2, 256, 0, stream>>>(t, W2sT, pf, N, 768, 768, 256, 256, 1.f / 3.f, 2);
  // ---- gating: pool_view, view_x, feat_x -> c [N,288] bf16 ----
  gate_k<<<N, 256, 0, stream>>>(t, pf, w2rs, vw1, vw2, fw1, fw2, c, pv);
  // ---- vf = relu(c@m1)@m2, sigmoid -> wall ----
  gemm_k<1, false><<<NB * 1, 256, 0, stream>>>(c, m1T, u, N, 288, 288, 128, 128, 1.f, 1);
  gemm_k<2, false><<<NB * 3, 256, 0, stream>>>(u, m2T, wall, N, 128, 128, 288, 288, 1.f, 3);
  // ---- z = concat(view_w*pool_view, feat_w*pool_feat) ----
  kz_k<<<N, 256, 0, stream>>>(wall, pf, pv, z);

  // ---- CSR build ----
  zero_k<<<196, 256, 0, stream>>>(cnt, N);
  hist_k<<<(E + 255) / 256, 256, 0, stream>>>(erow, cnt, E);
  s1_k<<<196, 256, 0, stream>>>(cnt, bsum, N);
  s2_k<<<1, 256, 0, stream>>>(bsum, bofs, 196);
  s3_k<<<196, 256, 0, stream>>>(cnt, bofs, starts, cursor, N, E);
  scat_k<<<(E + 255) / 256, 256, 0, stream>>>(erow, ecol, evalp, cursor, ccol, cval, E);

  // ---- 3-layer GCN: z = tanh(spmm(z) @ g) ----
  spmm_k<<<N, 256, 0, stream>>>(starts, ccol, cval, z, s);
  gemm_k<3, false><<<NB * 3, 256, 0, stream>>>(s, g0T, z, N, 288, 288, 288, 288, 1.f, 3);
  spmm_k<<<N, 256, 0, stream>>>(starts, ccol, cval, z, s);
  gemm_k<3, false><<<NB * 3, 256, 0, stream>>>(s, g1T, z, N, 288, 288, 288, 288, 1.f, 3);
  spmm_k<<<N, 256, 0, stream>>>(starts, ccol, cval, z, s);
  gemm_k<4, false><<<NB * 1, 256, 0, stream>>>(s, g2T, d_out, N, 288, 288, 10, 10, 1.f, 1);
}

// Round 5
// 1278.022 us; speedup vs baseline: 1.4287x; 1.4287x over previous
//
#include <hip/hip_runtime.h>
#include <hip/hip_bf16.h>
#include <cmath>
#include <cstdint>

using bf16 = __bf16;
typedef __bf16 bf16x8 __attribute__((ext_vector_type(8)));
typedef __bf16 bf16x4 __attribute__((ext_vector_type(4)));
typedef float f32x4 __attribute__((ext_vector_type(4)));

#define DEVI __device__ __forceinline__

// physical 16B-chunk index for logical (row m, chunk c) in a [128][32]-bf16 LDS
// tile, XOR-swizzled: 16-lane column reads spread over all 32 banks ~2-way
// (free, m136) instead of 16-way. XOR is an involution -> same map both sides.
DEVI int pcidx(int m, int c) { return (m << 2) + (c ^ ((m >> 1) & 3)); }

DEVI void gload16(const void* g, void* l) {
  __builtin_amdgcn_global_load_lds(
      (const __attribute__((address_space(1))) void*)g,
      (__attribute__((address_space(3))) void*)l, 16, 0, 0);
}

// ---------------------------------------------------------------------------
// GEMM: C[M x Ncols] = act( A[M x K] @ B[K x N] * scale )
// B stored transposed+padded: Bt[Npad][K] bf16, K multiple of 32.
// A: bf16 [Mpad][K] (AF32=false) staged via global_load_lds (dest wave-uniform
// base + lane*16, source pre-swizzled; rule #21), or fp32 [Mreal][ldA]
// (AF32=true) staged via registers with on-the-fly bf16 convert + K-tail pad.
// Grid: 1D, NB*NT blocks; n-tile fastest + bijective XCD chunk swizzle (m204).
// ACT: 0 = f32 store (x*scale), 1 = bf16 relu, 3 = bf16 tanh, 4 = f32 tanh,
//      5 = fused kz: bf16 sigmoid(x) * (col<3 ? pv[row,col] :
//                                        col>=32 ? pf[row,col-32] : 0)
// ---------------------------------------------------------------------------
template <int ACT, bool AF32>
__global__ __launch_bounds__(256) void gemm_k(
    const void* __restrict__ Ap, const bf16* __restrict__ Bt,
    void* __restrict__ Cp, int Mreal, int K, int ldA, int Ncols, int ldC,
    float scale, int NT, const float* __restrict__ pfx,
    const float* __restrict__ pvx) {
  __shared__ __align__(16) bf16 lA[128 * 32];
  __shared__ __align__(16) bf16 lB[128 * 32];
  const int tid = threadIdx.x;
  // ---- bijective XCD chunk swizzle (works for any nwg; ERRATA #11) ----
  const int nwg = gridDim.x;
  const int q8 = nwg >> 3, r8 = nwg & 7;
  const int xcd = blockIdx.x & 7, idx = blockIdx.x >> 3;
  const int wgid =
      (xcd < r8 ? xcd * (q8 + 1) : r8 * (q8 + 1) + (xcd - r8) * q8) + idx;
  const int m0 = (wgid / NT) * 128, n0 = (wgid % NT) * 128;

  const int w = tid >> 6, lane = tid & 63;
  const int wm = w >> 1, wn = w & 1;
  const int lm = lane & 15, lg = lane >> 4;

  f32x4 acc[4][4] = {};

  const int nkt = K / 32;
  for (int kt = 0; kt < nkt; ++kt) {
    const int k0 = kt * 32;
    // ---- B staging: 2 x global_load_lds, global source pre-swizzled ----
#pragma unroll
    for (int i = 0; i < 2; i++) {
      int q = i * 256 + tid;
      int row = q >> 2, slot = q & 3;
      int c = slot ^ ((row >> 1) & 3);
      const bf16* src = Bt + (size_t)(n0 + row) * K + k0 + c * 8;
      bf16* dst = lB + (size_t)(i * 256 + (tid & 192)) * 8;  // wave-uniform
      gload16(src, dst);
    }
    // ---- A staging ----
    if constexpr (AF32) {
      const float* Af = (const float*)Ap;
      int row = tid >> 1, h = tid & 1;
      int gm = m0 + row;
      int kb = k0 + h * 16;
      const float* Ar = Af + (size_t)gm * ldA;
      bf16x8 v0, v1;
      if (gm < Mreal && kb + 16 <= ldA) {
        f32x4 f0 = *(const f32x4*)(Ar + kb);
        f32x4 f1 = *(const f32x4*)(Ar + kb + 4);
        f32x4 f2 = *(const f32x4*)(Ar + kb + 8);
        f32x4 f3 = *(const f32x4*)(Ar + kb + 12);
#pragma unroll
        for (int j = 0; j < 4; j++) {
          v0[j] = (bf16)f0[j];
          v0[4 + j] = (bf16)f1[j];
          v1[j] = (bf16)f2[j];
          v1[4 + j] = (bf16)f3[j];
        }
      } else {
#pragma unroll
        for (int j = 0; j < 8; j++) {
          v0[j] = (bf16)((gm < Mreal && kb + j < ldA) ? Ar[kb + j] : 0.f);
          v1[j] = (bf16)((gm < Mreal && kb + 8 + j < ldA) ? Ar[kb + 8 + j] : 0.f);
        }
      }
      *(bf16x8*)&lA[(size_t)pcidx(row, h * 2) * 8] = v0;
      *(bf16x8*)&lA[(size_t)pcidx(row, h * 2 + 1) * 8] = v1;
    } else {
      const bf16* Ab = (const bf16*)Ap;
#pragma unroll
      for (int i = 0; i < 2; i++) {
        int q = i * 256 + tid;
        int row = q >> 2, slot = q & 3;
        int c = slot ^ ((row >> 1) & 3);
        const bf16* src = Ab + (size_t)(m0 + row) * K + k0 + c * 8;
        bf16* dst = lA + (size_t)(i * 256 + (tid & 192)) * 8;
        gload16(src, dst);
      }
    }
    asm volatile("s_waitcnt vmcnt(0)" ::: "memory");
    __syncthreads();
    // ---- compute: 8 ds_read_b128 + 16 MFMA per wave ----
    bf16x8 af[4], bfr[4];
#pragma unroll
    for (int mi = 0; mi < 4; ++mi) {
      int m = wm * 64 + mi * 16 + lm;
      af[mi] = *(const bf16x8*)&lA[(size_t)pcidx(m, lg) * 8];
    }
#pragma unroll
    for (int ni = 0; ni < 4; ++ni) {
      int n = wn * 64 + ni * 16 + lm;
      bfr[ni] = *(const bf16x8*)&lB[(size_t)pcidx(n, lg) * 8];
    }
#pragma unroll
    for (int mi = 0; mi < 4; ++mi)
#pragma unroll
      for (int ni = 0; ni < 4; ++ni)
        acc[mi][ni] = __builtin_amdgcn_mfma_f32_16x16x32_bf16(
            af[mi], bfr[ni], acc[mi][ni], 0, 0, 0);
    __syncthreads();
  }
  // ---- epilogue: D col = lane&15, row = (lane>>4)*4 + reg (m89-verified) ----
#pragma unroll
  for (int mi = 0; mi < 4; ++mi) {
#pragma unroll
    for (int ni = 0; ni < 4; ++ni) {
#pragma unroll
      for (int r = 0; r < 4; ++r) {
        int row = m0 + wm * 64 + mi * 16 + lg * 4 + r;
        int col = n0 + wn * 64 + ni * 16 + lm;
        if (row < Mreal && col < Ncols) {
          float x = acc[mi][ni][r] * scale;
          if constexpr (ACT == 0)
            ((float*)Cp)[(size_t)row * ldC + col] = x;
          else if constexpr (ACT == 1)
            ((bf16*)Cp)[(size_t)row * ldC + col] = (bf16)fmaxf(x, 0.f);
          else if constexpr (ACT == 3)
            ((bf16*)Cp)[(size_t)row * ldC + col] = (bf16)tanhf(x);
          else if constexpr (ACT == 4)
            ((float*)Cp)[(size_t)row * ldC + col] = tanhf(x);
          else if constexpr (ACT == 5) {
            float sig = 1.f / (1.f + __expf(-x));
            float mul;
            if (col >= 32) mul = pfx[(size_t)row * 256 + (col - 32)];
            else if (col < 3) mul = pvx[(size_t)row * 4 + col];
            else mul = 0.f;
            ((bf16*)Cp)[(size_t)row * ldC + col] = (bf16)(sig * mul);
          }
        }
      }
    }
  }
}

// ---------------------------------------------------------------------------
// Weight transpose+pad+convert: dst[n*Kp + cofs + k] =
//   (k<K && n<Nsrc) ? src[k*sN + n] : 0   for n<Np, k<W.
// 14 jobs cover all weights incl. the padded-row/col mappings for the
// [view(3) | pad(29) | feat(256)] layout.
// ---------------------------------------------------------------------------
struct WJob {
  const float* src;
  bf16* dst;
  int Np, W, K, Nsrc, sN, Kp, cofs, kch, blkEnd;
};
struct WJobs { WJob j[14]; };

__global__ void wcvt_k(WJobs J) {
  int b = blockIdx.x;
  int ji = 0;
  while (b >= J.j[ji].blkEnd) ji++;
  const WJob job = J.j[ji];
  int lb = b - (ji ? J.j[ji - 1].blkEnd : 0);
  int n = lb / job.kch, bk = lb % job.kch;
  int k = bk * 256 + (int)threadIdx.x;
  if (k >= job.W) return;
  float v = 0.f;
  if (k < job.K && n < job.Nsrc) v = job.src[(size_t)k * job.sN + n];
  job.dst[(size_t)n * job.Kp + job.cofs + k] = (bf16)v;
}

// w2rs[v*256+k] = sum_d w2_v[k][d]  (for the pool_view GEMV)
__global__ void w2rs_k(const float* w0, const float* w1, const float* w2,
                       float* out) {
  int v = blockIdx.x, k = threadIdx.x;
  const float* w = v == 0 ? w0 : (v == 1 ? w1 : w2);
  float s = 0.f;
  for (int d = 0; d < 256; d++) s += w[(size_t)k * 256 + d];
  out[v * 256 + k] = s;
}

// ---------------------------------------------------------------------------
// Gating, wave-per-node (4 nodes/block, no __syncthreads):
//   pool_view[n,v] = dot(t_v[n,:], w2rs_v)/256 ; view_x = sig(relu(pv@vw1)@vw2)
//   feat_x = sig(relu(pf@fw1)@fw2)
// writes c[n] = [view_x(3) | 0(29) | feat_x(256)] bf16 and pv[n,0..2] f32.
// ---------------------------------------------------------------------------
__global__ __launch_bounds__(256) void gate_k(
    const bf16* __restrict__ t, const float* __restrict__ pf,
    const float* __restrict__ w2rs, const float* __restrict__ vw1,
    const float* __restrict__ vw2, const float* __restrict__ fw1,
    const float* __restrict__ fw2, bf16* __restrict__ c,
    float* __restrict__ pv, int N) {
  __shared__ __align__(16) float pfs[4][260];  // 260: 16B-aligned rows
  __shared__ __align__(16) float usm[4][16];
  const int wid = threadIdx.x >> 6, lane = threadIdx.x & 63;
  const int n = blockIdx.x * 4 + wid;
  if (n >= N) return;
  const int g = lane >> 4, j = lane & 15;

  // stage pf row into this wave's LDS slice (wave-synchronous, no barrier)
  f32x4 pfv = *(const f32x4*)(pf + (size_t)n * 256 + lane * 4);
  *(f32x4*)&pfs[wid][lane * 4] = pfv;

  // ---- pool_view dots (vectorized bf16x4 * f32x4) ----
  size_t tb = (size_t)n * 768;
  bf16x4 t0 = *(const bf16x4*)(t + tb + lane * 4);
  bf16x4 t1 = *(const bf16x4*)(t + tb + 256 + lane * 4);
  bf16x4 t2 = *(const bf16x4*)(t + tb + 512 + lane * 4);
  f32x4 wr0 = *(const f32x4*)(w2rs + lane * 4);
  f32x4 wr1 = *(const f32x4*)(w2rs + 256 + lane * 4);
  f32x4 wr2 = *(const f32x4*)(w2rs + 512 + lane * 4);
  float s0 = 0.f, s1 = 0.f, s2 = 0.f;
#pragma unroll
  for (int cc = 0; cc < 4; cc++) {
    s0 += (float)t0[cc] * wr0[cc];
    s1 += (float)t1[cc] * wr1[cc];
    s2 += (float)t2[cc] * wr2[cc];
  }
#pragma unroll
  for (int o = 32; o > 0; o >>= 1) {
    s0 += __shfl_xor(s0, o);
    s1 += __shfl_xor(s1, o);
    s2 += __shfl_xor(s2, o);
  }
  const float p0 = s0 * (1.f / 256.f), p1 = s1 * (1.f / 256.f),
              p2 = s2 * (1.f / 256.f);
  const float av = fmaxf(p0 * vw1[0] + p1 * vw1[1] + p2 * vw1[2], 0.f);
  const float vx0 = 1.f / (1.f + __expf(-av * vw2[0]));
  const float vx1 = 1.f / (1.f + __expf(-av * vw2[1]));
  const float vx2 = 1.f / (1.f + __expf(-av * vw2[2]));

  // ---- u[j] = relu(sum_k pf[k] fw1[k][j]) ; group g covers k in [64g,64g+64)
  //      k order staggered by 8g -> 4 groups hit 4 distinct LDS banks ----
  __builtin_amdgcn_wave_barrier();
  float uj = 0.f;
#pragma unroll
  for (int kk = 0; kk < 64; kk++) {
    int k = g * 64 + ((kk + g * 8) & 63);
    uj += pfs[wid][k] * fw1[k * 16 + j];
  }
  uj += __shfl_xor(uj, 16);
  uj += __shfl_xor(uj, 32);
  uj = fmaxf(uj, 0.f);
  if (lane < 16) usm[wid][lane] = uj;
  __builtin_amdgcn_wave_barrier();

  // ---- fx[i] = sum_j u[j] fw2[j][i], lane covers i = lane*4..lane*4+3 ----
  float ur[16];
  *(f32x4*)&ur[0] = *(const f32x4*)&usm[wid][0];
  *(f32x4*)&ur[4] = *(const f32x4*)&usm[wid][4];
  *(f32x4*)&ur[8] = *(const f32x4*)&usm[wid][8];
  *(f32x4*)&ur[12] = *(const f32x4*)&usm[wid][12];
  f32x4 fx = {0.f, 0.f, 0.f, 0.f};
#pragma unroll
  for (int jj = 0; jj < 16; jj++) {
    f32x4 wv = *(const f32x4*)(fw2 + (size_t)jj * 256 + lane * 4);
#pragma unroll
    for (int cc = 0; cc < 4; cc++) fx[cc] += ur[jj] * wv[cc];
  }
  size_t cb = (size_t)n * 288;
  bf16x4 outv;
#pragma unroll
  for (int cc = 0; cc < 4; cc++)
    outv[cc] = (bf16)(1.f / (1.f + __expf(-fx[cc])));
  *(bf16x4*)(c + cb + 32 + lane * 4) = outv;
  if (lane < 8) {
    bf16x4 hv;
#pragma unroll
    for (int cc = 0; cc < 4; cc++) {
      int pos = lane * 4 + cc;
      float vv = pos == 0 ? vx0 : (pos == 1 ? vx1 : (pos == 2 ? vx2 : 0.f));
      hv[cc] = (bf16)vv;
    }
    *(bf16x4*)(c + cb + lane * 4) = hv;
  }
  if (lane < 3) pv[(size_t)n * 4 + lane] = lane == 0 ? p0 : (lane == 1 ? p1 : p2);
}

// ---------------- CSR build (counting sort by row) ----------------
__global__ void zero_k(int* p, int n) {
  int i = blockIdx.x * 256 + threadIdx.x;
  if (i < n) p[i] = 0;
}
__global__ void hist_k(const int* __restrict__ row, int* __restrict__ cnt, int E) {
  int e = blockIdx.x * 256 + threadIdx.x;
  if (e < E) atomicAdd(&cnt[row[e]], 1);
}
__global__ void s1_k(const int* cnt, int* bsum, int n) {
  __shared__ int sh[256];
  int i = blockIdx.x * 256 + threadIdx.x;
  sh[threadIdx.x] = (i < n) ? cnt[i] : 0;
  __syncthreads();
  for (int o = 128; o > 0; o >>= 1) {
    if ((int)threadIdx.x < o) sh[threadIdx.x] += sh[threadIdx.x + o];
    __syncthreads();
  }
  if (threadIdx.x == 0) bsum[blockIdx.x] = sh[0];
}
__global__ void s2_k(const int* bsum, int* bofs, int nb) {
  __shared__ int sh[256];
  int t = threadIdx.x;
  int v = (t < nb) ? bsum[t] : 0;
  sh[t] = v;
  __syncthreads();
  for (int o = 1; o < 256; o <<= 1) {
    int add = (t >= o) ? sh[t - o] : 0;
    __syncthreads();
    sh[t] += add;
    __syncthreads();
  }
  if (t < nb) bofs[t] = sh[t] - v;
}
__global__ void s3_k(const int* cnt, const int* bofs, int* starts, int* cursor,
                     int n, int total) {
  __shared__ int sh[256];
  int t = threadIdx.x, i = blockIdx.x * 256 + t;
  int v = (i < n) ? cnt[i] : 0;
  sh[t] = v;
  __syncthreads();
  for (int o = 1; o < 256; o <<= 1) {
    int add = (t >= o) ? sh[t - o] : 0;
    __syncthreads();
    sh[t] += add;
    __syncthreads();
  }
  if (i < n) {
    int ex = bofs[blockIdx.x] + sh[t] - v;
    starts[i] = ex;
    cursor[i] = ex;
  }
  if (i == 0) starts[n] = total;
}
__global__ void scat_k(const int* __restrict__ row, const int* __restrict__ col,
                       const float* __restrict__ val, int* __restrict__ cursor,
                       int* __restrict__ ccol, float* __restrict__ cval, int E) {
  int e = blockIdx.x * 256 + threadIdx.x;
  if (e < E) {
    int r = row[e];
    int p = atomicAdd(&cursor[r], 1);
    ccol[p] = col[e];
    cval[p] = val[e];
  }
}

// spmm: s[r,:] = sum_e val_e * z[col_e,:], one block/row, 288 cols, 4x unroll
__global__ __launch_bounds__(256) void spmm_k(
    const int* __restrict__ starts, const int* __restrict__ ccol,
    const float* __restrict__ cval, const bf16* __restrict__ z,
    bf16* __restrict__ s) {
  int r = blockIdx.x, t = threadIdx.x;
  int e0 = starts[r], e1 = starts[r + 1];
  float a0 = 0.f, a1 = 0.f;
  int e = e0;
  for (; e + 4 <= e1; e += 4) {
    int c0 = ccol[e], c1 = ccol[e + 1], c2 = ccol[e + 2], c3 = ccol[e + 3];
    float v0 = cval[e], v1 = cval[e + 1], v2 = cval[e + 2], v3 = cval[e + 3];
    const bf16* z0 = z + (size_t)c0 * 288;
    const bf16* z1 = z + (size_t)c1 * 288;
    const bf16* z2 = z + (size_t)c2 * 288;
    const bf16* z3 = z + (size_t)c3 * 288;
    float b0 = (float)z0[t], b1 = (float)z1[t], b2 = (float)z2[t],
          b3 = (float)z3[t];
    a0 += v0 * b0 + v1 * b1 + v2 * b2 + v3 * b3;
    if (t < 32) {
      a1 += v0 * (float)z0[256 + t] + v1 * (float)z1[256 + t] +
            v2 * (float)z2[256 + t] + v3 * (float)z3[256 + t];
    }
  }
  for (; e < e1; e++) {
    int cc = ccol[e];
    float v = cval[e];
    const bf16* zp = z + (size_t)cc * 288;
    a0 += v * (float)zp[t];
    if (t < 32) a1 += v * (float)zp[256 + t];
  }
  size_t sb = (size_t)r * 288;
  s[sb + t] = (bf16)a0;
  if (t < 32) s[sb + 256 + t] = (bf16)a1;
}

// ---------------------------------------------------------------------------
extern "C" void kernel_launch(void* const* d_in, const int* in_sizes, int n_in,
                              void* d_out, int out_size, void* d_ws,
                              size_t ws_size, hipStream_t stream) {
  const float* x0 = (const float*)d_in[0];
  const float* p0w1 = (const float*)d_in[1];
  const float* p0w2 = (const float*)d_in[2];
  const float* x1 = (const float*)d_in[3];
  const float* p1w1 = (const float*)d_in[4];
  const float* p1w2 = (const float*)d_in[5];
  const float* x2 = (const float*)d_in[6];
  const float* p2w1 = (const float*)d_in[7];
  const float* p2w2 = (const float*)d_in[8];
  const int* erow = (const int*)d_in[9];
  const int* ecol = (const int*)d_in[10];
  const float* evalp = (const float*)d_in[11];
  const float* vw1 = (const float*)d_in[12];
  const float* vw2 = (const float*)d_in[13];
  const float* fw1 = (const float*)d_in[14];
  const float* fw2 = (const float*)d_in[15];
  const float* m1 = (const float*)d_in[16];
  const float* m2 = (const float*)d_in[17];
  const float* g0 = (const float*)d_in[18];
  const float* g1 = (const float*)d_in[19];
  const float* g2 = (const float*)d_in[20];

  const int N = 50000;
  const int MP = 50048;  // 391 * 128
  const int NB = 391;
  const int E = in_sizes[9];

  char* p = (char*)d_ws;
  auto alloc = [&](size_t bytes) -> char* {
    char* r = p;
    p += (bytes + 255) & ~(size_t)255;
    return r;
  };
  bf16* t = (bf16*)alloc((size_t)MP * 768 * 2);  // 76.9 MB; dead after gate_k
  bf16* w1T0 = (bf16*)alloc((size_t)256 * 1024 * 2);
  bf16* w1T1 = (bf16*)alloc((size_t)256 * 832 * 2);
  bf16* w1T2 = (bf16*)alloc((size_t)256 * 640 * 2);
  bf16* W2sT = (bf16*)alloc((size_t)256 * 768 * 2);
  float* w2rs = (float*)alloc(768 * 4);
  bf16* m1T = (bf16*)alloc((size_t)128 * 288 * 2);
  bf16* m2T = (bf16*)alloc((size_t)384 * 128 * 2);
  bf16* g0T = (bf16*)alloc((size_t)384 * 288 * 2);
  bf16* g1T = (bf16*)alloc((size_t)384 * 288 * 2);
  bf16* g2T = (bf16*)alloc((size_t)128 * 288 * 2);
  float* pf = (float*)alloc((size_t)N * 256 * 4);
  float* pv = (float*)alloc((size_t)N * 4 * 4);
  bf16* c = (bf16*)alloc((size_t)MP * 288 * 2);
  int* cnt = (int*)alloc((size_t)50004 * 4);
  int* starts = (int*)alloc((size_t)50004 * 4);
  int* cursor = (int*)alloc((size_t)50004 * 4);
  int* bsum = (int*)alloc(1024);
  int* bofs = (int*)alloc(1024);
  int* ccol = (int*)alloc((size_t)E * 4);
  float* cval = (float*)alloc((size_t)E * 4);
  // aliases into t's region (t dead after gate_k; stream order serializes):
  //   u = t[0 .. MP*128)  (m1-gemm out, dead after m2-gemm)
  //   z = t[MP*416 .. MP*704)  (live through GCN; 704 <= 768)
  bf16* u = t;
  bf16* z = t + (size_t)MP * 416;
  bf16* s = c;  // c dead after the m1 GEMM; spmm output reuses it
  if ((size_t)(p - (char*)d_ws) > ws_size) return;  // ws too small: bail

  // ---- weight convert/transpose jobs ----
  WJobs J;
  auto setj = [&](int idx, const float* src, bf16* dst, int Np, int W, int K,
                  int Nsrc, int sN, int Kp, int cofs) {
    WJob& jj = J.j[idx];
    jj.src = src; jj.dst = dst; jj.Np = Np; jj.W = W; jj.K = K; jj.Nsrc = Nsrc;
    jj.sN = sN; jj.Kp = Kp; jj.cofs = cofs; jj.kch = (W + 255) / 256;
    jj.blkEnd = 0;
  };
  setj(0, p0w1, w1T0, 256, 1024, 1000, 256, 256, 1024, 0);
  setj(1, p1w1, w1T1, 256, 832, 800, 256, 256, 832, 0);
  setj(2, p2w1, w1T2, 256, 640, 600, 256, 256, 640, 0);
  setj(3, p0w2, W2sT, 256, 256, 256, 256, 256, 768, 0);
  setj(4, p1w2, W2sT, 256, 256, 256, 256, 256, 768, 256);
  setj(5, p2w2, W2sT, 256, 256, 256, 256, 256, 768, 512);
  // m1 rows -> [view(3) @0 | pad | feat(256) @32] of the padded-288 K layout
  setj(6, m1, m1T, 128, 32, 3, 128, 128, 288, 0);
  setj(7, m1 + 3 * 128, m1T, 128, 256, 256, 128, 128, 288, 32);
  // m2 cols -> padded-288 output layout (view @0..2, feat @32..287)
  setj(8, m2, m2T, 32, 128, 128, 3, 259, 128, 0);
  setj(9, m2 + 3, m2T + (size_t)32 * 128, 256, 128, 128, 256, 259, 128, 0);
  // g0 rows -> padded-288 K layout (matches z1 from fused kz epilogue)
  setj(10, g0, g0T, 384, 32, 3, 259, 259, 288, 0);
  setj(11, g0 + 3 * 259, g0T, 384, 256, 256, 259, 259, 288, 32);
  // g1, g2: contiguous-259 K layout (z2/z3 rows are contiguous)
  setj(12, g1, g1T, 384, 288, 259, 259, 259, 288, 0);
  setj(13, g2, g2T, 128, 288, 259, 10, 10, 288, 0);
  int cum = 0;
  for (int i = 0; i < 14; i++) {
    cum += J.j[i].Np * J.j[i].kch;
    J.j[i].blkEnd = cum;
  }
  wcvt_k<<<cum, 256, 0, stream>>>(J);
  w2rs_k<<<3, 256, 0, stream>>>(p0w2, p1w2, p2w2, w2rs);

  // ---- per-view projections: t_v = relu(x_v @ w1_v), bf16 [N,768] ----
  gemm_k<1, true><<<NB * 2, 256, 0, stream>>>(x0, w1T0, t, N, 1024, 1000, 256, 768, 1.f, 2, nullptr, nullptr);
  gemm_k<1, true><<<NB * 2, 256, 0, stream>>>(x1, w1T1, t + 256, N, 832, 800, 256, 768, 1.f, 2, nullptr, nullptr);
  gemm_k<1, true><<<NB * 2, 256, 0, stream>>>(x2, w1T2, t + 512, N, 640, 600, 256, 768, 1.f, 2, nullptr, nullptr);
  // ---- pool_feat = (t @ [w2_0;w2_1;w2_2]) / 3, f32 [N,256] ----
  gemm_k<0, false><<<NB * 2, 256, 0, stream>>>(t, W2sT, pf, N, 768, 768, 256, 256, 1.f / 3.f, 2, nullptr, nullptr);
  // ---- gating: pool_view, view_x, feat_x -> c [N,288] bf16 (padded-32) ----
  gate_k<<<(N + 3) / 4, 256, 0, stream>>>(t, pf, w2rs, vw1, vw2, fw1, fw2, c, pv, N);
  // ---- vf = relu(c@m1)@m2; fused kz epilogue writes z1 directly ----
  gemm_k<1, false><<<NB * 1, 256, 0, stream>>>(c, m1T, u, N, 288, 288, 128, 128, 1.f, 1, nullptr, nullptr);
  gemm_k<5, false><<<NB * 3, 256, 0, stream>>>(u, m2T, z, N, 128, 128, 288, 288, 1.f, 3, pf, pv);

  // ---- CSR build ----
  zero_k<<<196, 256, 0, stream>>>(cnt, N);
  hist_k<<<(E + 255) / 256, 256, 0, stream>>>(erow, cnt, E);
  s1_k<<<196, 256, 0, stream>>>(cnt, bsum, N);
  s2_k<<<1, 256, 0, stream>>>(bsum, bofs, 196);
  s3_k<<<196, 256, 0, stream>>>(cnt, bofs, starts, cursor, N, E);
  scat_k<<<(E + 255) / 256, 256, 0, stream>>>(erow, ecol, evalp, cursor, ccol, cval, E);

  // ---- 3-layer GCN: z = tanh(spmm(z) @ g) ----
  spmm_k<<<N, 256, 0, stream>>>(starts, ccol, cval, z, s);
  gemm_k<3, false><<<NB * 3, 256, 0, stream>>>(s, g0T, z, N, 288, 288, 288, 288, 1.f, 3, nullptr, nullptr);
  spmm_k<<<N, 256, 0, stream>>>(starts, ccol, cval, z, s);
  gemm_k<3, false><<<NB * 3, 256, 0, stream>>>(s, g1T, z, N, 288, 288, 288, 288, 1.f, 3, nullptr, nullptr);
  spmm_k<<<N, 256, 0, stream>>>(starts, ccol, cval, z, s);
  gemm_k<4, false><<<NB * 1, 256, 0, stream>>>(s, g2T, d_out, N, 288, 288, 10, 10, 1.f, 1, nullptr, nullptr);
}

// Round 8
// 1234.740 us; speedup vs baseline: 1.4788x; 1.0351x over previous
//
#include <hip/hip_runtime.h>
#include <hip/hip_bf16.h>
#include <cmath>
#include <cstdint>

using bf16 = __bf16;
typedef __bf16 bf16x8 __attribute__((ext_vector_type(8)));
typedef __bf16 bf16x4 __attribute__((ext_vector_type(4)));
typedef float f32x4 __attribute__((ext_vector_type(4)));

#define DEVI __device__ __forceinline__

// physical 16B-chunk index for logical (row m, chunk c) in a [128][32]-bf16 LDS
// tile, XOR-swizzled: 16-lane column reads spread over all 32 banks ~2-way
// (free, m136) instead of 16-way. XOR is an involution -> same map both sides.
DEVI int pcidx(int m, int c) { return (m << 2) + (c ^ ((m >> 1) & 3)); }

DEVI void gload16(const void* g, void* l) {
  __builtin_amdgcn_global_load_lds(
      (const __attribute__((address_space(1))) void*)g,
      (__attribute__((address_space(3))) void*)l, 16, 0, 0);
}

// bijective XCD chunk swizzle over a local grid of nwg (ERRATA #11 / m204)
DEVI int xcd_swz(int lb, int nwg) {
  int q8 = nwg >> 3, r8 = nwg & 7;
  int xcd = lb & 7, idx = lb >> 3;
  return (xcd < r8 ? xcd * (q8 + 1) : r8 * (q8 + 1) + (xcd - r8) * q8) + idx;
}

// ---------------------------------------------------------------------------
// bf16 GEMM: C[M x Ncols] = act( A[M x K] @ B[K x N] * scale )
// A bf16 [Mpad][K], B transposed+padded Bt[Npad][K] bf16, K mult of 32.
// Depth-1 double-buffered: loads for tile k+1 issued BEFORE compute of tile k;
// the compiler's pre-barrier vmcnt(0) drain lands after the MFMAs, so HBM/L2
// latency overlaps compute. One barrier per K-step.
// ACT: 0 = f32 store (x*scale), 1 = bf16 relu, 3 = bf16 tanh, 4 = f32 tanh,
//      5 = fused kz: bf16 sigmoid(x) * (col<3 ? pv[row,col] :
//                                        col>=32 ? pf[row,col-32] : 0)
// ---------------------------------------------------------------------------
template <int ACT>
__global__ __launch_bounds__(256) void gemm_k(
    const bf16* __restrict__ Ab, const bf16* __restrict__ Bt,
    void* __restrict__ Cp, int Mreal, int K, int Ncols, int ldC, float scale,
    int NT, const float* __restrict__ pfx, const float* __restrict__ pvx) {
  __shared__ __align__(16) bf16 lA[2][128 * 32];
  __shared__ __align__(16) bf16 lB[2][128 * 32];
  const int tid = threadIdx.x;
  const int wgid = xcd_swz(blockIdx.x, gridDim.x);
  const int m0 = (wgid / NT) * 128, n0 = (wgid % NT) * 128;

  const int w = tid >> 6, lane = tid & 63;
  const int wm = w >> 1, wn = w & 1;
  const int lm = lane & 15, lg = lane >> 4;

  f32x4 acc[4][4] = {};

  auto issueAB = [&](int buf, int k0) {
#pragma unroll
    for (int i = 0; i < 2; i++) {
      int q = i * 256 + tid;
      int row = q >> 2, slot = q & 3;
      int c = slot ^ ((row >> 1) & 3);
      gload16(Bt + (size_t)(n0 + row) * K + k0 + c * 8,
              &lB[buf][(size_t)(i * 256 + (tid & 192)) * 8]);
    }
#pragma unroll
    for (int i = 0; i < 2; i++) {
      int q = i * 256 + tid;
      int row = q >> 2, slot = q & 3;
      int c = slot ^ ((row >> 1) & 3);
      gload16(Ab + (size_t)(m0 + row) * K + k0 + c * 8,
              &lA[buf][(size_t)(i * 256 + (tid & 192)) * 8]);
    }
  };

  const int nkt = K / 32;
  issueAB(0, 0);
  __syncthreads();  // implicit vmcnt(0): DMA landed for all waves
  for (int kt = 0; kt < nkt; ++kt) {
    const int cur = kt & 1, nxt = cur ^ 1;
    if (kt + 1 < nkt) issueAB(nxt, (kt + 1) * 32);
    bf16x8 af[4], bfr[4];
#pragma unroll
    for (int mi = 0; mi < 4; ++mi) {
      int m = wm * 64 + mi * 16 + lm;
      af[mi] = *(const bf16x8*)&lA[cur][(size_t)pcidx(m, lg) * 8];
    }
#pragma unroll
    for (int ni = 0; ni < 4; ++ni) {
      int n = wn * 64 + ni * 16 + lm;
      bfr[ni] = *(const bf16x8*)&lB[cur][(size_t)pcidx(n, lg) * 8];
    }
#pragma unroll
    for (int mi = 0; mi < 4; ++mi)
#pragma unroll
      for (int ni = 0; ni < 4; ++ni)
        acc[mi][ni] = __builtin_amdgcn_mfma_f32_16x16x32_bf16(
            af[mi], bfr[ni], acc[mi][ni], 0, 0, 0);
    if (kt + 1 < nkt) __syncthreads();  // drains next-tile DMA after compute
  }
  // ---- epilogue: D col = lane&15, row = (lane>>4)*4 + reg (m89-verified) ----
#pragma unroll
  for (int mi = 0; mi < 4; ++mi) {
#pragma unroll
    for (int ni = 0; ni < 4; ++ni) {
#pragma unroll
      for (int r = 0; r < 4; ++r) {
        int row = m0 + wm * 64 + mi * 16 + lg * 4 + r;
        int col = n0 + wn * 64 + ni * 16 + lm;
        if (row < Mreal && col < Ncols) {
          float x = acc[mi][ni][r] * scale;
          if constexpr (ACT == 0)
            ((float*)Cp)[(size_t)row * ldC + col] = x;
          else if constexpr (ACT == 1)
            ((bf16*)Cp)[(size_t)row * ldC + col] = (bf16)fmaxf(x, 0.f);
          else if constexpr (ACT == 3)
            ((bf16*)Cp)[(size_t)row * ldC + col] = (bf16)tanhf(x);
          else if constexpr (ACT == 4)
            ((float*)Cp)[(size_t)row * ldC + col] = tanhf(x);
          else if constexpr (ACT == 5) {
            float sig = 1.f / (1.f + __expf(-x));
            float mul;
            if (col >= 32) mul = pfx[(size_t)row * 256 + (col - 32)];
            else if (col < 3) mul = pvx[(size_t)row * 4 + col];
            else mul = 0.f;
            ((bf16*)Cp)[(size_t)row * ldC + col] = (bf16)(sig * mul);
          }
        }
      }
    }
  }
}

// ---------------------------------------------------------------------------
// Fused 3-view projection GEMM: one launch, 3 jobs (t_v = relu(x_v @ w1_v)).
// A fp32 [N][ldA] reg-staged (T14 issue-early/write-late) with on-the-fly
// bf16 cvt + K-tail zero-pad; same depth-1 double-buffer as gemm_k.
// 3x grid => ~5 blocks/CU (LDS-capped) for latency hiding.
// ---------------------------------------------------------------------------
struct GJob { const float* A; const bf16* Bt; bf16* C; int K, ldA, blkEnd; };
struct GJobs { GJob j[3]; };

__global__ __launch_bounds__(256) void gemm3_k(GJobs G, int Mreal) {
  __shared__ __align__(16) bf16 lA[2][128 * 32];
  __shared__ __align__(16) bf16 lB[2][128 * 32];
  const int tid = threadIdx.x;
  int ji = 0;
  while ((int)blockIdx.x >= G.j[ji].blkEnd) ji++;
  const GJob job = G.j[ji];
  const int jstart = ji ? G.j[ji - 1].blkEnd : 0;
  const int wgid = xcd_swz(blockIdx.x - jstart, job.blkEnd - jstart);
  const int m0 = (wgid >> 1) * 128, n0 = (wgid & 1) * 128;
  const int K = job.K, ldA = job.ldA;

  const int w = tid >> 6, lane = tid & 63;
  const int wm = w >> 1, wn = w & 1;
  const int lm = lane & 15, lg = lane >> 4;

  const int arow = tid >> 1, h = tid & 1;
  const int gm = m0 + arow;
  const float* Ar = job.A + (size_t)gm * ldA;

  f32x4 f[4];  // in-flight A prefetch
  auto issueA = [&](int k0) {
    int kb = k0 + h * 16;
    if (gm < Mreal && kb + 16 <= ldA) {
      f[0] = *(const f32x4*)(Ar + kb);
      f[1] = *(const f32x4*)(Ar + kb + 4);
      f[2] = *(const f32x4*)(Ar + kb + 8);
      f[3] = *(const f32x4*)(Ar + kb + 12);
    } else {
#pragma unroll
      for (int q = 0; q < 4; q++)
#pragma unroll
        for (int j = 0; j < 4; j++)
          f[q][j] = (gm < Mreal && kb + q * 4 + j < ldA) ? Ar[kb + q * 4 + j] : 0.f;
    }
  };
  auto writeA = [&](int buf) {  // cvt (waits the loads) + swizzled ds_write
    bf16x8 v0, v1;
#pragma unroll
    for (int j = 0; j < 4; j++) {
      v0[j] = (bf16)f[0][j];
      v0[4 + j] = (bf16)f[1][j];
      v1[j] = (bf16)f[2][j];
      v1[4 + j] = (bf16)f[3][j];
    }
    *(bf16x8*)&lA[buf][(size_t)pcidx(arow, h * 2) * 8] = v0;
    *(bf16x8*)&lA[buf][(size_t)pcidx(arow, h * 2 + 1) * 8] = v1;
  };
  auto issueB = [&](int buf, int k0) {
#pragma unroll
    for (int i = 0; i < 2; i++) {
      int q = i * 256 + tid;
      int row = q >> 2, slot = q & 3;
      int c = slot ^ ((row >> 1) & 3);
      gload16(job.Bt + (size_t)(n0 + row) * K + k0 + c * 8,
              &lB[buf][(size_t)(i * 256 + (tid & 192)) * 8]);
    }
  };

  f32x4 acc[4][4] = {};
  const int nkt = K / 32;
  issueB(0, 0);
  issueA(0);
  writeA(0);
  __syncthreads();
  for (int kt = 0; kt < nkt; ++kt) {
    const int cur = kt & 1, nxt = cur ^ 1;
    if (kt + 1 < nkt) {
      issueB(nxt, (kt + 1) * 32);
      issueA((kt + 1) * 32);
    }
    bf16x8 af[4], bfr[4];
#pragma unroll
    for (int mi = 0; mi < 4; ++mi) {
      int m = wm * 64 + mi * 16 + lm;
      af[mi] = *(const bf16x8*)&lA[cur][(size_t)pcidx(m, lg) * 8];
    }
#pragma unroll
    for (int ni = 0; ni < 4; ++ni) {
      int n = wn * 64 + ni * 16 + lm;
      bfr[ni] = *(const bf16x8*)&lB[cur][(size_t)pcidx(n, lg) * 8];
    }
#pragma unroll
    for (int mi = 0; mi < 4; ++mi)
#pragma unroll
      for (int ni = 0; ni < 4; ++ni)
        acc[mi][ni] = __builtin_amdgcn_mfma_f32_16x16x32_bf16(
            af[mi], bfr[ni], acc[mi][ni], 0, 0, 0);
    if (kt + 1 < nkt) {
      writeA(nxt);     // cvt forces vmcnt wait AFTER the MFMAs
      __syncthreads();
    }
  }
#pragma unroll
  for (int mi = 0; mi < 4; ++mi) {
#pragma unroll
    for (int ni = 0; ni < 4; ++ni) {
#pragma unroll
      for (int r = 0; r < 4; ++r) {
        int row = m0 + wm * 64 + mi * 16 + lg * 4 + r;
        int col = n0 + wn * 64 + ni * 16 + lm;
        if (row < Mreal && col < 256)
          job.C[(size_t)row * 768 + col] = (bf16)fmaxf(acc[mi][ni][r], 0.f);
      }
    }
  }
}

// ---------------------------------------------------------------------------
// Weight transpose+pad+convert: dst[n*Kp + cofs + k] =
//   (k<K && n<Nsrc) ? src[k*sN + n] : 0   for n<Np, k<W.
// ---------------------------------------------------------------------------
struct WJob {
  const float* src;
  bf16* dst;
  int Np, W, K, Nsrc, sN, Kp, cofs, kch, blkEnd;
};
struct WJobs { WJob j[14]; };

__global__ void wcvt_k(WJobs J) {
  int b = blockIdx.x;
  int ji = 0;
  while (b >= J.j[ji].blkEnd) ji++;
  const WJob job = J.j[ji];
  int lb = b - (ji ? J.j[ji - 1].blkEnd : 0);
  int n = lb / job.kch, bk = lb % job.kch;
  int k = bk * 256 + (int)threadIdx.x;
  if (k >= job.W) return;
  float v = 0.f;
  if (k < job.K && n < job.Nsrc) v = job.src[(size_t)k * job.sN + n];
  job.dst[(size_t)n * job.Kp + job.cofs + k] = (bf16)v;
}

// w2rs[v*256+k] = sum_d w2_v[k][d]  (for the pool_view GEMV)
__global__ void w2rs_k(const float* w0, const float* w1, const float* w2,
                       float* out) {
  int v = blockIdx.x, k = threadIdx.x;
  const float* w = v == 0 ? w0 : (v == 1 ? w1 : w2);
  float s = 0.f;
  for (int d = 0; d < 256; d++) s += w[(size_t)k * 256 + d];
  out[v * 256 + k] = s;
}

// ---------------------------------------------------------------------------
// Gating, wave-per-node (4 nodes/block, no __syncthreads):
// writes c[n] = [view_x(3) | 0(29) | feat_x(256)] bf16 and pv[n,0..2] f32.
// ---------------------------------------------------------------------------
__global__ __launch_bounds__(256) void gate_k(
    const bf16* __restrict__ t, const float* __restrict__ pf,
    const float* __restrict__ w2rs, const float* __restrict__ vw1,
    const float* __restrict__ vw2, const float* __restrict__ fw1,
    const float* __restrict__ fw2, bf16* __restrict__ c,
    float* __restrict__ pv, int N) {
  __shared__ __align__(16) float pfs[4][260];
  __shared__ __align__(16) float usm[4][16];
  const int wid = threadIdx.x >> 6, lane = threadIdx.x & 63;
  const int n = blockIdx.x * 4 + wid;
  if (n >= N) return;
  const int g = lane >> 4, j = lane & 15;

  f32x4 pfv = *(const f32x4*)(pf + (size_t)n * 256 + lane * 4);
  *(f32x4*)&pfs[wid][lane * 4] = pfv;

  size_t tb = (size_t)n * 768;
  bf16x4 t0 = *(const bf16x4*)(t + tb + lane * 4);
  bf16x4 t1 = *(const bf16x4*)(t + tb + 256 + lane * 4);
  bf16x4 t2 = *(const bf16x4*)(t + tb + 512 + lane * 4);
  f32x4 wr0 = *(const f32x4*)(w2rs + lane * 4);
  f32x4 wr1 = *(const f32x4*)(w2rs + 256 + lane * 4);
  f32x4 wr2 = *(const f32x4*)(w2rs + 512 + lane * 4);
  float s0 = 0.f, s1 = 0.f, s2 = 0.f;
#pragma unroll
  for (int cc = 0; cc < 4; cc++) {
    s0 += (float)t0[cc] * wr0[cc];
    s1 += (float)t1[cc] * wr1[cc];
    s2 += (float)t2[cc] * wr2[cc];
  }
#pragma unroll
  for (int o = 32; o > 0; o >>= 1) {
    s0 += __shfl_xor(s0, o);
    s1 += __shfl_xor(s1, o);
    s2 += __shfl_xor(s2, o);
  }
  const float p0 = s0 * (1.f / 256.f), p1 = s1 * (1.f / 256.f),
              p2 = s2 * (1.f / 256.f);
  const float av = fmaxf(p0 * vw1[0] + p1 * vw1[1] + p2 * vw1[2], 0.f);
  const float vx0 = 1.f / (1.f + __expf(-av * vw2[0]));
  const float vx1 = 1.f / (1.f + __expf(-av * vw2[1]));
  const float vx2 = 1.f / (1.f + __expf(-av * vw2[2]));

  __builtin_amdgcn_wave_barrier();
  float uj = 0.f;
#pragma unroll
  for (int kk = 0; kk < 64; kk++) {
    int k = g * 64 + ((kk + g * 8) & 63);
    uj += pfs[wid][k] * fw1[k * 16 + j];
  }
  uj += __shfl_xor(uj, 16);
  uj += __shfl_xor(uj, 32);
  uj = fmaxf(uj, 0.f);
  if (lane < 16) usm[wid][lane] = uj;
  __builtin_amdgcn_wave_barrier();

  float ur[16];
  *(f32x4*)&ur[0] = *(const f32x4*)&usm[wid][0];
  *(f32x4*)&ur[4] = *(const f32x4*)&usm[wid][4];
  *(f32x4*)&ur[8] = *(const f32x4*)&usm[wid][8];
  *(f32x4*)&ur[12] = *(const f32x4*)&usm[wid][12];
  f32x4 fx = {0.f, 0.f, 0.f, 0.f};
#pragma unroll
  for (int jj = 0; jj < 16; jj++) {
    f32x4 wv = *(const f32x4*)(fw2 + (size_t)jj * 256 + lane * 4);
#pragma unroll
    for (int cc = 0; cc < 4; cc++) fx[cc] += ur[jj] * wv[cc];
  }
  size_t cb = (size_t)n * 288;
  bf16x4 outv;
#pragma unroll
  for (int cc = 0; cc < 4; cc++)
    outv[cc] = (bf16)(1.f / (1.f + __expf(-fx[cc])));
  *(bf16x4*)(c + cb + 32 + lane * 4) = outv;
  if (lane < 8) {
    bf16x4 hv;
#pragma unroll
    for (int cc = 0; cc < 4; cc++) {
      int pos = lane * 4 + cc;
      float vv = pos == 0 ? vx0 : (pos == 1 ? vx1 : (pos == 2 ? vx2 : 0.f));
      hv[cc] = (bf16)vv;
    }
    *(bf16x4*)(c + cb + lane * 4) = hv;
  }
  if (lane < 3) pv[(size_t)n * 4 + lane] = lane == 0 ? p0 : (lane == 1 ? p1 : p2);
}

// ---------------- CSR build (counting sort by row) ----------------
__global__ void zero_k(int* p, int n) {
  int i = blockIdx.x * 256 + threadIdx.x;
  if (i < n) p[i] = 0;
}
__global__ void hist_k(const int* __restrict__ row, int* __restrict__ cnt, int E) {
  int e = blockIdx.x * 256 + threadIdx.x;
  if (e < E) atomicAdd(&cnt[row[e]], 1);
}
__global__ void s1_k(const int* cnt, int* bsum, int n) {
  __shared__ int sh[256];
  int i = blockIdx.x * 256 + threadIdx.x;
  sh[threadIdx.x] = (i < n) ? cnt[i] : 0;
  __syncthreads();
  for (int o = 128; o > 0; o >>= 1) {
    if ((int)threadIdx.x < o) sh[threadIdx.x] += sh[threadIdx.x + o];
    __syncthreads();
  }
  if (threadIdx.x == 0) bsum[blockIdx.x] = sh[0];
}
__global__ void s2_k(const int* bsum, int* bofs, int nb) {
  __shared__ int sh[256];
  int t = threadIdx.x;
  int v = (t < nb) ? bsum[t] : 0;
  sh[t] = v;
  __syncthreads();
  for (int o = 1; o < 256; o <<= 1) {
    int add = (t >= o) ? sh[t - o] : 0;
    __syncthreads();
    sh[t] += add;
    __syncthreads();
  }
  if (t < nb) bofs[t] = sh[t] - v;
}
__global__ void s3_k(const int* cnt, const int* bofs, int* starts, int* cursor,
                     int n, int total) {
  __shared__ int sh[256];
  int t = threadIdx.x, i = blockIdx.x * 256 + t;
  int v = (i < n) ? cnt[i] : 0;
  sh[t] = v;
  __syncthreads();
  for (int o = 1; o < 256; o <<= 1) {
    int add = (t >= o) ? sh[t - o] : 0;
    __syncthreads();
    sh[t] += add;
    __syncthreads();
  }
  if (i < n) {
    int ex = bofs[blockIdx.x] + sh[t] - v;
    starts[i] = ex;
    cursor[i] = ex;
  }
  if (i == 0) starts[n] = total;
}
__global__ void scat_k(const int* __restrict__ row, const int* __restrict__ col,
                       const float* __restrict__ val, int* __restrict__ cursor,
                       int* __restrict__ ccol, float* __restrict__ cval, int E) {
  int e = blockIdx.x * 256 + threadIdx.x;
  if (e < E) {
    int r = row[e];
    int p = atomicAdd(&cursor[r], 1);
    ccol[p] = col[e];
    cval[p] = val[e];
  }
}

// spmm: s[r,:] = sum_e val_e * z[col_e,:], one block/row, 288 cols, 4x unroll
__global__ __launch_bounds__(256) void spmm_k(
    const int* __restrict__ starts, const int* __restrict__ ccol,
    const float* __restrict__ cval, const bf16* __restrict__ z,
    bf16* __restrict__ s) {
  int r = blockIdx.x, t = threadIdx.x;
  int e0 = starts[r], e1 = starts[r + 1];
  float a0 = 0.f, a1 = 0.f;
  int e = e0;
  for (; e + 4 <= e1; e += 4) {
    int c0 = ccol[e], c1 = ccol[e + 1], c2 = ccol[e + 2], c3 = ccol[e + 3];
    float v0 = cval[e], v1 = cval[e + 1], v2 = cval[e + 2], v3 = cval[e + 3];
    const bf16* z0 = z + (size_t)c0 * 288;
    const bf16* z1 = z + (size_t)c1 * 288;
    const bf16* z2 = z + (size_t)c2 * 288;
    const bf16* z3 = z + (size_t)c3 * 288;
    float b0 = (float)z0[t], b1 = (float)z1[t], b2 = (float)z2[t],
          b3 = (float)z3[t];
    a0 += v0 * b0 + v1 * b1 + v2 * b2 + v3 * b3;
    if (t < 32) {
      a1 += v0 * (float)z0[256 + t] + v1 * (float)z1[256 + t] +
            v2 * (float)z2[256 + t] + v3 * (float)z3[256 + t];
    }
  }
  for (; e < e1; e++) {
    int cc = ccol[e];
    float v = cval[e];
    const bf16* zp = z + (size_t)cc * 288;
    a0 += v * (float)zp[t];
    if (t < 32) a1 += v * (float)zp[256 + t];
  }
  size_t sb = (size_t)r * 288;
  s[sb + t] = (bf16)a0;
  if (t < 32) s[sb + 256 + t] = (bf16)a1;
}

// ---------------------------------------------------------------------------
extern "C" void kernel_launch(void* const* d_in, const int* in_sizes, int n_in,
                              void* d_out, int out_size, void* d_ws,
                              size_t ws_size, hipStream_t stream) {
  const float* x0 = (const float*)d_in[0];
  const float* p0w1 = (const float*)d_in[1];
  const float* p0w2 = (const float*)d_in[2];
  const float* x1 = (const float*)d_in[3];
  const float* p1w1 = (const float*)d_in[4];
  const float* p1w2 = (const float*)d_in[5];
  const float* x2 = (const float*)d_in[6];
  const float* p2w1 = (const float*)d_in[7];
  const float* p2w2 = (const float*)d_in[8];
  const int* erow = (const int*)d_in[9];
  const int* ecol = (const int*)d_in[10];
  const float* evalp = (const float*)d_in[11];
  const float* vw1 = (const float*)d_in[12];
  const float* vw2 = (const float*)d_in[13];
  const float* fw1 = (const float*)d_in[14];
  const float* fw2 = (const float*)d_in[15];
  const float* m1 = (const float*)d_in[16];
  const float* m2 = (const float*)d_in[17];
  const float* g0 = (const float*)d_in[18];
  const float* g1 = (const float*)d_in[19];
  const float* g2 = (const float*)d_in[20];

  const int N = 50000;
  const int MP = 50048;  // 391 * 128
  const int NB = 391;
  const int E = in_sizes[9];

  char* p = (char*)d_ws;
  auto alloc = [&](size_t bytes) -> char* {
    char* r = p;
    p += (bytes + 255) & ~(size_t)255;
    return r;
  };
  bf16* t = (bf16*)alloc((size_t)MP * 768 * 2);  // 76.9 MB; dead after gate_k
  bf16* w1T0 = (bf16*)alloc((size_t)256 * 1024 * 2);
  bf16* w1T1 = (bf16*)alloc((size_t)256 * 832 * 2);
  bf16* w1T2 = (bf16*)alloc((size_t)256 * 640 * 2);
  bf16* W2sT = (bf16*)alloc((size_t)256 * 768 * 2);
  float* w2rs = (float*)alloc(768 * 4);
  bf16* m1T = (bf16*)alloc((size_t)128 * 288 * 2);
  bf16* m2T = (bf16*)alloc((size_t)384 * 128 * 2);
  bf16* g0T = (bf16*)alloc((size_t)384 * 288 * 2);
  bf16* g1T = (bf16*)alloc((size_t)384 * 288 * 2);
  bf16* g2T = (bf16*)alloc((size_t)128 * 288 * 2);
  float* pf = (float*)alloc((size_t)N * 256 * 4);
  float* pv = (float*)alloc((size_t)N * 4 * 4);
  bf16* c = (bf16*)alloc((size_t)MP * 288 * 2);
  int* cnt = (int*)alloc((size_t)50004 * 4);
  int* starts = (int*)alloc((size_t)50004 * 4);
  int* cursor = (int*)alloc((size_t)50004 * 4);
  int* bsum = (int*)alloc(1024);
  int* bofs = (int*)alloc(1024);
  int* ccol = (int*)alloc((size_t)E * 4);
  float* cval = (float*)alloc((size_t)E * 4);
  // aliases into t's region (t dead after gate_k; stream order serializes):
  bf16* u = t;                          // m1-gemm out, dead after m2-gemm
  bf16* z = t + (size_t)MP * 416;       // live through GCN; 704 <= 768
  bf16* s = c;  // c dead after the m1 GEMM; spmm output reuses it
  if ((size_t)(p - (char*)d_ws) > ws_size) return;  // ws too small: bail

  // ---- weight convert/transpose jobs ----
  WJobs J;
  auto setj = [&](int idx, const float* src, bf16* dst, int Np, int W, int K,
                  int Nsrc, int sN, int Kp, int cofs) {
    WJob& jj = J.j[idx];
    jj.src = src; jj.dst = dst; jj.Np = Np; jj.W = W; jj.K = K; jj.Nsrc = Nsrc;
    jj.sN = sN; jj.Kp = Kp; jj.cofs = cofs; jj.kch = (W + 255) / 256;
    jj.blkEnd = 0;
  };
  setj(0, p0w1, w1T0, 256, 1024, 1000, 256, 256, 1024, 0);
  setj(1, p1w1, w1T1, 256, 832, 800, 256, 256, 832, 0);
  setj(2, p2w1, w1T2, 256, 640, 600, 256, 256, 640, 0);
  setj(3, p0w2, W2sT, 256, 256, 256, 256, 256, 768, 0);
  setj(4, p1w2, W2sT, 256, 256, 256, 256, 256, 768, 256);
  setj(5, p2w2, W2sT, 256, 256, 256, 256, 256, 768, 512);
  // m1 rows -> [view(3) @0 | pad | feat(256) @32] of the padded-288 K layout
  setj(6, m1, m1T, 128, 32, 3, 128, 128, 288, 0);
  setj(7, m1 + 3 * 128, m1T, 128, 256, 256, 128, 128, 288, 32);
  // m2 cols -> padded-288 output layout (view @0..2, feat @32..287)
  setj(8, m2, m2T, 32, 128, 128, 3, 259, 128, 0);
  setj(9, m2 + 3, m2T + (size_t)32 * 128, 256, 128, 128, 256, 259, 128, 0);
  // g0 rows -> padded-288 K layout (matches z1 from fused kz epilogue)
  setj(10, g0, g0T, 384, 32, 3, 259, 259, 288, 0);
  setj(11, g0 + 3 * 259, g0T, 384, 256, 256, 259, 259, 288, 32);
  // g1, g2: contiguous-259 K layout (z2/z3 rows are contiguous)
  setj(12, g1, g1T, 384, 288, 259, 259, 259, 288, 0);
  setj(13, g2, g2T, 128, 288, 259, 10, 10, 288, 0);
  int cum = 0;
  for (int i = 0; i < 14; i++) {
    cum += J.j[i].Np * J.j[i].kch;
    J.j[i].blkEnd = cum;
  }
  wcvt_k<<<cum, 256, 0, stream>>>(J);
  w2rs_k<<<3, 256, 0, stream>>>(p0w2, p1w2, p2w2, w2rs);

  // ---- fused per-view projections: t = [relu(x_v @ w1_v)]_v, bf16 [N,768] --
  GJobs G;
  G.j[0] = {x0, w1T0, t, 1024, 1000, NB * 2};
  G.j[1] = {x1, w1T1, t + 256, 832, 800, NB * 4};
  G.j[2] = {x2, w1T2, t + 512, 640, 600, NB * 6};
  gemm3_k<<<NB * 6, 256, 0, stream>>>(G, N);
  // ---- pool_feat = (t @ [w2_0;w2_1;w2_2]) / 3, f32 [N,256] ----
  gemm_k<0><<<NB * 2, 256, 0, stream>>>(t, W2sT, pf, N, 768, 256, 256, 1.f / 3.f, 2, nullptr, nullptr);
  // ---- gating: pool_view, view_x, feat_x -> c [N,288] bf16 (padded-32) ----
  gate_k<<<(N + 3) / 4, 256, 0, stream>>>(t, pf, w2rs, vw1, vw2, fw1, fw2, c, pv, N);
  // ---- vf = relu(c@m1)@m2; fused kz epilogue writes z directly ----
  gemm_k<1><<<NB * 1, 256, 0, stream>>>(c, m1T, u, N, 288, 128, 128, 1.f, 1, nullptr, nullptr);
  gemm_k<5><<<NB * 3, 256, 0, stream>>>(u, m2T, z, N, 128, 288, 288, 1.f, 3, pf, pv);

  // ---- CSR build ----
  zero_k<<<196, 256, 0, stream>>>(cnt, N);
  hist_k<<<(E + 255) / 256, 256, 0, stream>>>(erow, cnt, E);
  s1_k<<<196, 256, 0, stream>>>(cnt, bsum, N);
  s2_k<<<1, 256, 0, stream>>>(bsum, bofs, 196);
  s3_k<<<196, 256, 0, stream>>>(cnt, bofs, starts, cursor, N, E);
  scat_k<<<(E + 255) / 256, 256, 0, stream>>>(erow, ecol, evalp, cursor, ccol, cval, E);

  // ---- 3-layer GCN: z = tanh(spmm(z) @ g) ----
  spmm_k<<<N, 256, 0, stream>>>(starts, ccol, cval, z, s);
  gemm_k<3><<<NB * 3, 256, 0, stream>>>(s, g0T, z, N, 288, 288, 288, 1.f, 3, nullptr, nullptr);
  spmm_k<<<N, 256, 0, stream>>>(starts, ccol, cval, z, s);
  gemm_k<3><<<NB * 3, 256, 0, stream>>>(s, g1T, z, N, 288, 288, 288, 1.f, 3, nullptr, nullptr);
  spmm_k<<<N, 256, 0, stream>>>(starts, ccol, cval, z, s);
  gemm_k<4><<<NB * 1, 256, 0, stream>>>(s, g2T, d_out, N, 288, 10, 10, 1.f, 1, nullptr, nullptr);
}